// Round 7
// baseline (171.822 us; speedup 1.0000x reference)
//
#include <hip/hip_runtime.h>
#include <hip/hip_bf16.h>

typedef __hip_bfloat16 bf16;
typedef __attribute__((ext_vector_type(8))) short s8v;   // 8 bf16 = 4 VGPR (MFMA A/B frag)
typedef __attribute__((ext_vector_type(4))) float f4v;   // MFMA C/D frag

__device__ __forceinline__ ushort f2u(float f) {
    bf16 h = __float2bfloat16(f);
    return *(ushort*)&h;
}

// ---------------------------------------------------------------------------
// B=4, C=256, H=W=64, N=4096. All inputs/outputs fp32; internal bf16.
// ws: cat bf16 [16384][512]   @ 0          (16 MiB)
//     Qb  bf16 [16384][32]    @ 16777216   ( 1 MiB)
//     Kb  bf16 [16384][32]    @ 17825792   ( 1 MiB)
//     Vf  bf16 frag-ordered   @ 18874368   ( 8 MiB)
//     Wf  bf16 frag-ordered   @ 27262976   ( 320 KiB)
// Vf: element (b,c,n) at b<<20 + (n>>5)*8192 + (c>>4)*512 + ((n>>3)&3)*128
//     + (c&15)*8 + (n&7)  -> MFMA B-frag = contiguous 1KB per wave.
// Wf: element (o,k) at (k>>5)*10240 + (o>>4)*512 + ((k>>3)&3)*128 + (o&15)*8
//     + (k&7)             -> same property.
// MFMA 16x16x32 bf16 layouts (m89/m120-verified):
//   A: lane holds A[m=lane&15][k=(lane>>4)*8+j]
//   B: lane holds B[k=(lane>>4)*8+j][n=lane&15]
//   C/D: lane holds D[row=(lane>>4)*4+r][col=lane&15]
// ---------------------------------------------------------------------------

// Kernel 0: W fp32 -> frag-ordered bf16 (one frag per block, 64 threads).
__global__ __launch_bounds__(64) void wcvt_kernel(
    const float* __restrict__ wb, const float* __restrict__ wc,
    const float* __restrict__ wd, ushort* __restrict__ Wf) {
    int ot = blockIdx.x;         // 0..19
    int kc = blockIdx.y;         // 0..15
    int l = threadIdx.x;
    int o = ot * 16 + (l & 15);
    int k0 = kc * 32 + (l >> 4) * 8;
    const float* wr = (o < 32) ? wb + (size_t)o * 512
                    : (o < 64) ? wc + (size_t)(o - 32) * 512
                               : wd + (size_t)(o - 64) * 512;
    float4 f0 = *(const float4*)(wr + k0);
    float4 f1 = *(const float4*)(wr + k0 + 4);
    ushort tmp[8] = {f2u(f0.x), f2u(f0.y), f2u(f0.z), f2u(f0.w),
                     f2u(f1.x), f2u(f1.y), f2u(f1.z), f2u(f1.w)};
    *(uint4*)(Wf + kc * 10240 + ot * 512 + l * 8) = *(uint4*)tmp;
}

// Kernel 1: 3x3 avg(/9, include-pad) + 3x3 max (unchanged from r6).
__global__ __launch_bounds__(256) void pool_kernel(const float* __restrict__ x,
                                                   ushort* __restrict__ cat) {
    __shared__ float Xs[3][64][66];
    int tid = threadIdx.x;
    int bid = blockIdx.x;
    int b = bid >> 8, h = (bid >> 2) & 63, cg = bid & 3;
    bool hasU = (h > 0), hasD = (h < 63);
    #pragma unroll
    for (int pp = 0; pp < 12; ++pp) {
        int linear = pp * 256 + tid;
        int w4 = linear & 15;
        int cs = (linear >> 4) & 63;
        int dh = linear >> 10;
        int hh = h + dh - 1;
        float4 f = {0.f, 0.f, 0.f, 0.f};
        if ((unsigned)hh < 64u)
            f = *(const float4*)(x + ((size_t)(b * 256 + cg * 64 + cs)) * 4096
                                 + hh * 64 + w4 * 4);
        Xs[dh][w4 * 4 + 0][cs] = f.x;
        Xs[dh][w4 * 4 + 1][cs] = f.y;
        Xs[dh][w4 * 4 + 2][cs] = f.z;
        Xs[dh][w4 * 4 + 3][cs] = f.w;
    }
    __syncthreads();
    int cs = tid & 63, ws = tid >> 6;
    float vs[18], vm[18];
    #pragma unroll
    for (int j = 0; j < 18; ++j) {
        int w = ws * 16 - 1 + j;
        if ((unsigned)w < 64u) {
            float u = Xs[0][w][cs], m = Xs[1][w][cs], d = Xs[2][w][cs];
            vs[j] = u + m + d;
            float mx = m;
            if (hasU) mx = fmaxf(mx, u);
            if (hasD) mx = fmaxf(mx, d);
            vm[j] = mx;
        } else { vs[j] = 0.f; vm[j] = -3.4e38f; }
    }
    size_t nb = ((size_t)b * 4096 + h * 64 + ws * 16) * 512 + cg * 64 + cs;
    #pragma unroll
    for (int i = 0; i < 16; ++i) {
        float sum = vs[i] + vs[i + 1] + vs[i + 2];
        float mx  = fmaxf(fmaxf(vm[i], vm[i + 1]), vm[i + 2]);
        cat[nb + (size_t)i * 512]       = f2u(sum * (1.f / 9.f));
        cat[nb + (size_t)i * 512 + 256] = f2u(mx);
    }
}

// Kernel 2: single-pass projections. 512 blocks x (32n x 320o), 4 waves;
// wave = 32n x 80o (5 o-tiles). cat read ONCE; W B-frags direct from Wf.
__global__ __launch_bounds__(256, 2) void proj_kernel(
    const ushort* __restrict__ cat, const ushort* __restrict__ Wf,
    const float* __restrict__ bb, const float* __restrict__ bc,
    const float* __restrict__ bd,
    ushort* __restrict__ Qb, ushort* __restrict__ Kb, ushort* __restrict__ Vf) {
    __shared__ __align__(16) ushort As[32][72];
    __shared__ __align__(16) ushort Vls[256][40];   // [c][n_local 32 + pad]
    int tid = threadIdx.x;
    int l = tid & 63, w = tid >> 6;
    int lm = l & 15, q = l >> 4;
    int n0 = blockIdx.x * 32;
    f4v acc[2][5];
    #pragma unroll
    for (int mt = 0; mt < 2; ++mt)
        #pragma unroll
        for (int ot = 0; ot < 5; ++ot)
            #pragma unroll
            for (int i = 0; i < 4; ++i) acc[mt][ot][i] = 0.f;

    const ushort* wfb = Wf + (w * 5) * 512 + l * 8;
    int sr = tid >> 3, sko = (tid & 7) * 8;          // staging map
    const ushort* srow = cat + (size_t)(n0 + sr) * 512 + sko;

    for (int kc = 0; kc < 8; ++kc) {
        *(uint4*)&As[sr][sko] = *(const uint4*)(srow + kc * 64);
        __syncthreads();
        #pragma unroll
        for (int ks = 0; ks < 2; ++ks) {
            int kci = kc * 2 + ks;
            s8v bf[5];
            #pragma unroll
            for (int ot = 0; ot < 5; ++ot)
                bf[ot] = *(const s8v*)(wfb + kci * 10240 + ot * 512);
            s8v a0 = *(const s8v*)&As[lm][ks * 32 + q * 8];
            s8v a1 = *(const s8v*)&As[16 + lm][ks * 32 + q * 8];
            #pragma unroll
            for (int ot = 0; ot < 5; ++ot) {
                acc[0][ot] = __builtin_amdgcn_mfma_f32_16x16x32_bf16(a0, bf[ot], acc[0][ot], 0, 0, 0);
                acc[1][ot] = __builtin_amdgcn_mfma_f32_16x16x32_bf16(a1, bf[ot], acc[1][ot], 0, 0, 0);
            }
        }
        __syncthreads();
    }
    // epilogue
    #pragma unroll
    for (int ot = 0; ot < 5; ++ot) {
        int o = w * 80 + ot * 16 + lm;
        if (o < 32) {
            float bias = bb[o];
            #pragma unroll
            for (int mt = 0; mt < 2; ++mt)
                #pragma unroll
                for (int r = 0; r < 4; ++r)
                    Qb[(size_t)(n0 + mt * 16 + q * 4 + r) * 32 + o]
                        = f2u(acc[mt][ot][r] + bias);
        } else if (o < 64) {
            float bias = bc[o - 32];
            #pragma unroll
            for (int mt = 0; mt < 2; ++mt)
                #pragma unroll
                for (int r = 0; r < 4; ++r)
                    Kb[(size_t)(n0 + mt * 16 + q * 4 + r) * 32 + (o - 32)]
                        = f2u(acc[mt][ot][r] + bias);
        } else {
            int c = o - 64;
            float bias = bd[c];
            #pragma unroll
            for (int mt = 0; mt < 2; ++mt) {
                ushort tmp[4];
                #pragma unroll
                for (int r = 0; r < 4; ++r) tmp[r] = f2u(acc[mt][ot][r] + bias);
                *(uint2*)&Vls[c][mt * 16 + q * 4] = *(uint2*)tmp;
            }
        }
    }
    __syncthreads();
    // Vf stores: lane=c-fast mapping -> each wave writes a full contiguous 1KB frag
    {
        int bidx = n0 >> 12;
        size_t fb = ((size_t)bidx << 20) + (size_t)((n0 & 4095) >> 5) * 8192 + l * 8;
        #pragma unroll
        for (int i = 0; i < 4; ++i) {
            int cb = w * 4 + i;
            *(uint4*)(Vf + fb + cb * 512) = *(const uint4*)&Vls[cb * 16 + lm][q * 8];
        }
    }
}

// Kernel 3: MFMA flash attention + residual. 256 blocks (1/CU), 512 threads
// (8 waves = 2 waves/SIMD). S^T scores (mfma(K,Q)) -> P write is ds_write_b64;
// PV k-halves split across wave pairs (kh=w>>2), combined once at epilogue.
// Q/K/V frags direct global; LDS = P round-trip only; ONE barrier per tile.
__global__ __launch_bounds__(512, 2) void attn_kernel(
    const ushort* __restrict__ Qb, const ushort* __restrict__ Kb,
    const ushort* __restrict__ Vf, const float* __restrict__ x,
    const float* __restrict__ alphap, float* __restrict__ out) {
    __shared__ __align__(16) ushort Ps[2][64][72];   // 36.9 KB
    __shared__ float Obuf[4][64][17];                // 17.4 KB (epilogue combine)
    __shared__ float Lpart[4][64];
    __shared__ float Lrow[64];
    int tid = threadIdx.x;
    int l = tid & 63, w = tid >> 6;                  // 8 waves
    int lm = l & 15, q = l >> 4;
    int nsw = w & 3, kh = w >> 2;
    int bid = blockIdx.x;
    int xcd = bid & 7;
    int b = xcd & 3;
    int midx = (bid >> 3) + ((xcd >> 2) << 5);       // 0..63
    int m0 = midx << 6;
    size_t bN = (size_t)b << 12;

    // Q frags (B-operand of S^T): rows m = m0 + kh*32 + mt*16 + lm
    s8v Qf[2];
    {
        const ushort* qb = Qb + (bN + m0 + kh * 32) * 32;
        Qf[0] = *(const s8v*)(qb + (size_t)(lm) * 32 + q * 8);
        Qf[1] = *(const s8v*)(qb + (size_t)(16 + lm) * 32 + q * 8);
    }
    const ushort* kbp = Kb + (bN + nsw * 16 + lm) * 32 + q * 8;
    const ushort* vfp = Vf + ((size_t)b << 20) + kh * 8192 + (nsw * 4) * 512 + l * 8;

    f4v acc[4][4];
    #pragma unroll
    for (int mt = 0; mt < 4; ++mt)
        #pragma unroll
        for (int ct = 0; ct < 4; ++ct)
            #pragma unroll
            for (int i = 0; i < 4; ++i) acc[mt][ct][i] = 0.f;
    float La0 = 0.f, La1 = 0.f;

    s8v kfA, kfB, vfA[4], vfB[4];
    kfA = *(const s8v*)kbp;
    #pragma unroll
    for (int ct = 0; ct < 4; ++ct) vfA[ct] = *(const s8v*)(vfp + ct * 512);

#define TILE_BODY(TT, KF, VF, KFN, VFN, DOPF)                                     \
    {                                                                             \
        int p = (TT) & 1;                                                         \
        f4v S0 = {0.f, 0.f, 0.f, 0.f}, S1 = {0.f, 0.f, 0.f, 0.f};                 \
        S0 = __builtin_amdgcn_mfma_f32_16x16x32_bf16(KF, Qf[0], S0, 0, 0, 0);     \
        S1 = __builtin_amdgcn_mfma_f32_16x16x32_bf16(KF, Qf[1], S1, 0, 0, 0);     \
        ushort e0[4], e1[4];                                                      \
        _Pragma("unroll")                                                         \
        for (int r = 0; r < 4; ++r) {                                             \
            float f0 = __expf(fminf(S0[r], 60.f));                                \
            float f1 = __expf(fminf(S1[r], 60.f));                                \
            La0 += f0; La1 += f1;                                                 \
            e0[r] = f2u(f0); e1[r] = f2u(f1);                                     \
        }                                                                         \
        *(uint2*)&Ps[p][kh * 32 + lm][nsw * 16 + q * 4]      = *(uint2*)e0;       \
        *(uint2*)&Ps[p][kh * 32 + 16 + lm][nsw * 16 + q * 4] = *(uint2*)e1;       \
        __syncthreads();                                                          \
        if (DOPF) {                                                               \
            KFN = *(const s8v*)(kbp + (size_t)((TT) + 1) * 2048);                 \
            const ushort* vn = vfp + (size_t)((TT) + 1) * 16384;                  \
            _Pragma("unroll")                                                     \
            for (int ct = 0; ct < 4; ++ct)                                        \
                VFN[ct] = *(const s8v*)(vn + ct * 512);                           \
        }                                                                         \
        s8v Af0 = *(const s8v*)&Ps[p][lm][kh * 32 + q * 8];                       \
        s8v Af1 = *(const s8v*)&Ps[p][16 + lm][kh * 32 + q * 8];                  \
        s8v Af2 = *(const s8v*)&Ps[p][32 + lm][kh * 32 + q * 8];                  \
        s8v Af3 = *(const s8v*)&Ps[p][48 + lm][kh * 32 + q * 8];                  \
        _Pragma("unroll")                                                         \
        for (int ct = 0; ct < 4; ++ct) {                                          \
            acc[0][ct] = __builtin_amdgcn_mfma_f32_16x16x32_bf16(Af0, VF[ct], acc[0][ct], 0, 0, 0); \
            acc[1][ct] = __builtin_amdgcn_mfma_f32_16x16x32_bf16(Af1, VF[ct], acc[1][ct], 0, 0, 0); \
            acc[2][ct] = __builtin_amdgcn_mfma_f32_16x16x32_bf16(Af2, VF[ct], acc[2][ct], 0, 0, 0); \
            acc[3][ct] = __builtin_amdgcn_mfma_f32_16x16x32_bf16(Af3, VF[ct], acc[3][ct], 0, 0, 0); \
        }                                                                         \
    }

    for (int t = 0; t < 64; t += 2) {
        TILE_BODY(t,     kfA, vfA, kfB, vfB, true);
        TILE_BODY(t + 1, kfB, vfB, kfA, vfA, (t + 2) < 64);
    }
#undef TILE_BODY

    // L: reduce over the 4 q-lane groups (n-direction), then across nsw waves
    La0 += __shfl_xor(La0, 16, 64); La0 += __shfl_xor(La0, 32, 64);
    La1 += __shfl_xor(La1, 16, 64); La1 += __shfl_xor(La1, 32, 64);
    if (q == 0) {
        Lpart[nsw][kh * 32 + lm]      = La0;
        Lpart[nsw][kh * 32 + 16 + lm] = La1;
    }
    __syncthreads();
    if (tid < 64)
        Lrow[tid] = Lpart[0][tid] + Lpart[1][tid] + Lpart[2][tid] + Lpart[3][tid];
    __syncthreads();
    // combine k-halves: kh=1 waves push their partial O through LDS
    #pragma unroll
    for (int ct = 0; ct < 4; ++ct) {
        if (kh == 1) {
            #pragma unroll
            for (int mt = 0; mt < 4; ++mt)
                #pragma unroll
                for (int r = 0; r < 4; ++r)
                    Obuf[nsw][mt * 16 + q * 4 + r][lm] = acc[mt][ct][r];
        }
        __syncthreads();
        if (kh == 0) {
            #pragma unroll
            for (int mt = 0; mt < 4; ++mt)
                #pragma unroll
                for (int r = 0; r < 4; ++r)
                    acc[mt][ct][r] += Obuf[nsw][mt * 16 + q * 4 + r][lm];
        }
        __syncthreads();
    }
    // epilogue (kh==0 waves): out = alpha*(acc/L) + (1-alpha)*x
    if (kh == 0) {
        float alpha = alphap[0];
        float ra = 1.f - alpha;
        #pragma unroll
        for (int mt = 0; mt < 4; ++mt) {
            float L0 = Lrow[mt * 16 + q * 4 + 0];
            float L1 = Lrow[mt * 16 + q * 4 + 1];
            float L2 = Lrow[mt * 16 + q * 4 + 2];
            float L3 = Lrow[mt * 16 + q * 4 + 3];
            #pragma unroll
            for (int ct = 0; ct < 4; ++ct) {
                int cc = nsw * 64 + ct * 16 + lm;
                size_t base = ((size_t)(b * 256 + cc)) * 4096 + m0 + mt * 16 + q * 4;
                float4 xv = *(const float4*)(x + base);
                float4 ov;
                ov.x = alpha * (acc[mt][ct][0] / L0) + ra * xv.x;
                ov.y = alpha * (acc[mt][ct][1] / L1) + ra * xv.y;
                ov.z = alpha * (acc[mt][ct][2] / L2) + ra * xv.z;
                ov.w = alpha * (acc[mt][ct][3] / L3) + ra * xv.w;
                *(float4*)(out + base) = ov;
            }
        }
    }
}

extern "C" void kernel_launch(void* const* d_in, const int* in_sizes, int n_in,
                              void* d_out, int out_size, void* d_ws, size_t ws_size,
                              hipStream_t stream) {
    const float* x  = (const float*)d_in[0];
    const float* wb = (const float*)d_in[1];
    const float* bb = (const float*)d_in[2];
    const float* wc = (const float*)d_in[3];
    const float* bc = (const float*)d_in[4];
    const float* wd = (const float*)d_in[5];
    const float* bd = (const float*)d_in[6];
    const float* al = (const float*)d_in[7];
    float* out = (float*)d_out;

    char* ws = (char*)d_ws;
    ushort* cat = (ushort*)ws;                    // 16 MiB
    ushort* Qb  = (ushort*)(ws + 16777216);       //  1 MiB
    ushort* Kb  = (ushort*)(ws + 17825792);       //  1 MiB
    ushort* Vf  = (ushort*)(ws + 18874368);       //  8 MiB (frag-ordered)
    ushort* Wf  = (ushort*)(ws + 27262976);       //  320 KiB (frag-ordered)

    wcvt_kernel<<<dim3(20, 16), dim3(64), 0, stream>>>(wb, wc, wd, Wf);
    pool_kernel<<<dim3(1024), dim3(256), 0, stream>>>(x, cat);
    proj_kernel<<<dim3(512), dim3(256), 0, stream>>>(cat, Wf, bb, bc, bd,
                                                     Qb, Kb, Vf);
    attn_kernel<<<dim3(256), dim3(512), 0, stream>>>(Qb, Kb, Vf, x, al, out);
}

// Round 8
// 164.128 us; speedup vs baseline: 1.0469x; 1.0469x over previous
//
#include <hip/hip_runtime.h>
#include <hip/hip_bf16.h>

typedef __hip_bfloat16 bf16;
typedef __attribute__((ext_vector_type(8))) short s8v;   // 8 bf16 = 4 VGPR (MFMA A/B frag)
typedef __attribute__((ext_vector_type(4))) float f4v;   // MFMA C/D frag

__device__ __forceinline__ ushort f2u(float f) {
    bf16 h = __float2bfloat16(f);
    return *(ushort*)&h;
}

// ---------------------------------------------------------------------------
// B=4, C=256, H=W=64, N=4096. All inputs/outputs fp32; internal bf16.
// ws: cat bf16 [16384][512]   @ 0          (16 MiB)
//     Qb  bf16 [16384][32]    @ 16777216   ( 1 MiB)
//     Kb  bf16 [16384][32]    @ 17825792   ( 1 MiB)
//     Vf  bf16 frag-ordered   @ 18874368   ( 8 MiB)
//     Wf  bf16 frag-ordered   @ 27262976   ( 320 KiB)
// Vf: element (b,c,n) at b<<20 + (n>>5)*8192 + (c>>4)*512 + ((n>>3)&3)*128
//     + (c&15)*8 + (n&7)  -> MFMA B-frag = contiguous 1KB per wave.
// Wf: element (o,k) at (k>>5)*10240 + (o>>4)*512 + ((k>>3)&3)*128 + (o&15)*8
//     + (k&7)             -> same property.
// MFMA 16x16x32 bf16 layouts (m89/m120-verified):
//   A: lane holds A[m=lane&15][k=(lane>>4)*8+j]
//   B: lane holds B[k=(lane>>4)*8+j][n=lane&15]
//   C/D: lane holds D[row=(lane>>4)*4+r][col=lane&15]
// ---------------------------------------------------------------------------

// Kernel 1: 3x3 avg(/9, include-pad) + 3x3 max; blocks >=1024 do the W
// fp32->bf16 frag-order conversion (folded wcvt: one fewer dispatch).
__global__ __launch_bounds__(256) void pool_kernel(
    const float* __restrict__ x, ushort* __restrict__ cat,
    const float* __restrict__ wb, const float* __restrict__ wc,
    const float* __restrict__ wd, ushort* __restrict__ Wf) {
    int bid = blockIdx.x;
    int tid = threadIdx.x;
    if (bid >= 1024) {            // wcvt tail: 80 blocks x 4 frags
        int f = (bid - 1024) * 4 + (tid >> 6);   // 0..319
        int l = tid & 63;
        int ot = f % 20, kc = f / 20;
        int o = ot * 16 + (l & 15);
        int k0 = kc * 32 + (l >> 4) * 8;
        const float* wr = (o < 32) ? wb + (size_t)o * 512
                        : (o < 64) ? wc + (size_t)(o - 32) * 512
                                   : wd + (size_t)(o - 64) * 512;
        float4 f0 = *(const float4*)(wr + k0);
        float4 f1 = *(const float4*)(wr + k0 + 4);
        ushort tmp[8] = {f2u(f0.x), f2u(f0.y), f2u(f0.z), f2u(f0.w),
                         f2u(f1.x), f2u(f1.y), f2u(f1.z), f2u(f1.w)};
        *(uint4*)(Wf + kc * 10240 + ot * 512 + l * 8) = *(uint4*)tmp;
        return;
    }
    __shared__ float Xs[3][64][66];
    int b = bid >> 8, h = (bid >> 2) & 63, cg = bid & 3;
    bool hasU = (h > 0), hasD = (h < 63);
    #pragma unroll
    for (int pp = 0; pp < 12; ++pp) {
        int linear = pp * 256 + tid;
        int w4 = linear & 15;
        int cs = (linear >> 4) & 63;
        int dh = linear >> 10;
        int hh = h + dh - 1;
        float4 f = {0.f, 0.f, 0.f, 0.f};
        if ((unsigned)hh < 64u)
            f = *(const float4*)(x + ((size_t)(b * 256 + cg * 64 + cs)) * 4096
                                 + hh * 64 + w4 * 4);
        Xs[dh][w4 * 4 + 0][cs] = f.x;
        Xs[dh][w4 * 4 + 1][cs] = f.y;
        Xs[dh][w4 * 4 + 2][cs] = f.z;
        Xs[dh][w4 * 4 + 3][cs] = f.w;
    }
    __syncthreads();
    int cs = tid & 63, ws = tid >> 6;
    float vs[18], vm[18];
    #pragma unroll
    for (int j = 0; j < 18; ++j) {
        int w = ws * 16 - 1 + j;
        if ((unsigned)w < 64u) {
            float u = Xs[0][w][cs], m = Xs[1][w][cs], d = Xs[2][w][cs];
            vs[j] = u + m + d;
            float mx = m;
            if (hasU) mx = fmaxf(mx, u);
            if (hasD) mx = fmaxf(mx, d);
            vm[j] = mx;
        } else { vs[j] = 0.f; vm[j] = -3.4e38f; }
    }
    size_t nb = ((size_t)b * 4096 + h * 64 + ws * 16) * 512 + cg * 64 + cs;
    #pragma unroll
    for (int i = 0; i < 16; ++i) {
        float sum = vs[i] + vs[i + 1] + vs[i + 2];
        float mx  = fmaxf(fmaxf(vm[i], vm[i + 1]), vm[i + 2]);
        cat[nb + (size_t)i * 512]       = f2u(sum * (1.f / 9.f));
        cat[nb + (size_t)i * 512 + 256] = f2u(mx);
    }
}

// Kernel 2: single-pass projections (unchanged from r7).
__global__ __launch_bounds__(256, 2) void proj_kernel(
    const ushort* __restrict__ cat, const ushort* __restrict__ Wf,
    const float* __restrict__ bb, const float* __restrict__ bc,
    const float* __restrict__ bd,
    ushort* __restrict__ Qb, ushort* __restrict__ Kb, ushort* __restrict__ Vf) {
    __shared__ __align__(16) ushort As[32][72];
    __shared__ __align__(16) ushort Vls[256][40];
    int tid = threadIdx.x;
    int l = tid & 63, w = tid >> 6;
    int lm = l & 15, q = l >> 4;
    int n0 = blockIdx.x * 32;
    f4v acc[2][5];
    #pragma unroll
    for (int mt = 0; mt < 2; ++mt)
        #pragma unroll
        for (int ot = 0; ot < 5; ++ot)
            #pragma unroll
            for (int i = 0; i < 4; ++i) acc[mt][ot][i] = 0.f;

    const ushort* wfb = Wf + (w * 5) * 512 + l * 8;
    int sr = tid >> 3, sko = (tid & 7) * 8;
    const ushort* srow = cat + (size_t)(n0 + sr) * 512 + sko;

    for (int kc = 0; kc < 8; ++kc) {
        *(uint4*)&As[sr][sko] = *(const uint4*)(srow + kc * 64);
        __syncthreads();
        #pragma unroll
        for (int ks = 0; ks < 2; ++ks) {
            int kci = kc * 2 + ks;
            s8v bf[5];
            #pragma unroll
            for (int ot = 0; ot < 5; ++ot)
                bf[ot] = *(const s8v*)(wfb + kci * 10240 + ot * 512);
            s8v a0 = *(const s8v*)&As[lm][ks * 32 + q * 8];
            s8v a1 = *(const s8v*)&As[16 + lm][ks * 32 + q * 8];
            #pragma unroll
            for (int ot = 0; ot < 5; ++ot) {
                acc[0][ot] = __builtin_amdgcn_mfma_f32_16x16x32_bf16(a0, bf[ot], acc[0][ot], 0, 0, 0);
                acc[1][ot] = __builtin_amdgcn_mfma_f32_16x16x32_bf16(a1, bf[ot], acc[1][ot], 0, 0, 0);
            }
        }
        __syncthreads();
    }
    #pragma unroll
    for (int ot = 0; ot < 5; ++ot) {
        int o = w * 80 + ot * 16 + lm;
        if (o < 32) {
            float bias = bb[o];
            #pragma unroll
            for (int mt = 0; mt < 2; ++mt)
                #pragma unroll
                for (int r = 0; r < 4; ++r)
                    Qb[(size_t)(n0 + mt * 16 + q * 4 + r) * 32 + o]
                        = f2u(acc[mt][ot][r] + bias);
        } else if (o < 64) {
            float bias = bc[o - 32];
            #pragma unroll
            for (int mt = 0; mt < 2; ++mt)
                #pragma unroll
                for (int r = 0; r < 4; ++r)
                    Kb[(size_t)(n0 + mt * 16 + q * 4 + r) * 32 + (o - 32)]
                        = f2u(acc[mt][ot][r] + bias);
        } else {
            int c = o - 64;
            float bias = bd[c];
            #pragma unroll
            for (int mt = 0; mt < 2; ++mt) {
                ushort tmp[4];
                #pragma unroll
                for (int r = 0; r < 4; ++r) tmp[r] = f2u(acc[mt][ot][r] + bias);
                *(uint2*)&Vls[c][mt * 16 + q * 4] = *(uint2*)tmp;
            }
        }
    }
    __syncthreads();
    {
        int bidx = n0 >> 12;
        size_t fb = ((size_t)bidx << 20) + (size_t)((n0 & 4095) >> 5) * 8192 + l * 8;
        #pragma unroll
        for (int i = 0; i < 4; ++i) {
            int cb = w * 4 + i;
            *(uint4*)(Vf + fb + cb * 512) = *(const uint4*)&Vls[cb * 16 + lm][q * 8];
        }
    }
}

// Kernel 3: MFMA flash attention + residual. 256 blocks, 512 threads (8 waves).
// Software-pipelined: each barrier-phase holds scores+exp(t+1) (VALU) AND
// PV(t) (MFMA) as independent work. One barrier per tile. K prefetch dist 2,
// V dist 1, register ping-pong via 2x unroll.
__global__ __launch_bounds__(512, 2) void attn_kernel(
    const ushort* __restrict__ Qb, const ushort* __restrict__ Kb,
    const ushort* __restrict__ Vf, const float* __restrict__ x,
    const float* __restrict__ alphap, float* __restrict__ out) {
    __shared__ __align__(16) ushort Ps[2][64][72];
    __shared__ float Obuf[4][64][17];
    __shared__ float Lpart[4][64];
    __shared__ float Lrow[64];
    int tid = threadIdx.x;
    int l = tid & 63, w = tid >> 6;
    int lm = l & 15, q = l >> 4;
    int nsw = w & 3, kh = w >> 2;
    int bid = blockIdx.x;
    int xcd = bid & 7;
    int b = xcd & 3;
    int midx = (bid >> 3) + ((xcd >> 2) << 5);
    int m0 = midx << 6;
    size_t bN = (size_t)b << 12;

    s8v Qf[2];
    {
        const ushort* qb = Qb + (bN + m0 + kh * 32) * 32;
        Qf[0] = *(const s8v*)(qb + (size_t)(lm) * 32 + q * 8);
        Qf[1] = *(const s8v*)(qb + (size_t)(16 + lm) * 32 + q * 8);
    }
    const ushort* kbp = Kb + (bN + nsw * 16 + lm) * 32 + q * 8;
    const ushort* vfp = Vf + ((size_t)b << 20) + kh * 8192 + (nsw * 4) * 512 + l * 8;

    f4v acc[4][4];
    #pragma unroll
    for (int mt = 0; mt < 4; ++mt)
        #pragma unroll
        for (int ct = 0; ct < 4; ++ct)
            #pragma unroll
            for (int i = 0; i < 4; ++i) acc[mt][ct][i] = 0.f;
    float La0 = 0.f, La1 = 0.f;

    // prologue: kf0 = tile0, kf1 = tile1, vfA = tile0; compute P(0)
    s8v kf0 = *(const s8v*)kbp;
    s8v kf1 = *(const s8v*)(kbp + 2048);
    s8v vfA[4], vfB[4];
    #pragma unroll
    for (int ct = 0; ct < 4; ++ct) vfA[ct] = *(const s8v*)(vfp + ct * 512);
    {
        f4v S0 = {0.f, 0.f, 0.f, 0.f}, S1 = {0.f, 0.f, 0.f, 0.f};
        S0 = __builtin_amdgcn_mfma_f32_16x16x32_bf16(kf0, Qf[0], S0, 0, 0, 0);
        S1 = __builtin_amdgcn_mfma_f32_16x16x32_bf16(kf0, Qf[1], S1, 0, 0, 0);
        ushort e0[4], e1[4];
        #pragma unroll
        for (int r = 0; r < 4; ++r) {
            float f0 = __expf(fminf(S0[r], 60.f));
            float f1 = __expf(fminf(S1[r], 60.f));
            La0 += f0; La1 += f1;
            e0[r] = f2u(f0); e1[r] = f2u(f1);
        }
        *(uint2*)&Ps[0][kh * 32 + lm][nsw * 16 + q * 4]      = *(uint2*)e0;
        *(uint2*)&Ps[0][kh * 32 + 16 + lm][nsw * 16 + q * 4] = *(uint2*)e1;
    }
    __syncthreads();

// Phase(t): scores+exp(t+1)->Ps[1-p] (regs only; Ps[1-p] free since barrier
// t-1); prefetch kf(t+2), vf(t+1); Af<-Ps[p]; PV(t); barrier.
#define TILE_BODY(TT, KFS, KFP, VCUR, VNXT)                                       \
    {                                                                             \
        int p = (TT) & 1;                                                         \
        if ((TT) < 63) {                                                          \
            f4v S0 = {0.f, 0.f, 0.f, 0.f}, S1 = {0.f, 0.f, 0.f, 0.f};             \
            S0 = __builtin_amdgcn_mfma_f32_16x16x32_bf16(KFS, Qf[0], S0, 0, 0, 0);\
            S1 = __builtin_amdgcn_mfma_f32_16x16x32_bf16(KFS, Qf[1], S1, 0, 0, 0);\
            ushort e0[4], e1[4];                                                  \
            _Pragma("unroll")                                                     \
            for (int r = 0; r < 4; ++r) {                                         \
                float f0 = __expf(fminf(S0[r], 60.f));                            \
                float f1 = __expf(fminf(S1[r], 60.f));                            \
                La0 += f0; La1 += f1;                                             \
                e0[r] = f2u(f0); e1[r] = f2u(f1);                                 \
            }                                                                     \
            *(uint2*)&Ps[1 - p][kh * 32 + lm][nsw * 16 + q * 4]      = *(uint2*)e0;\
            *(uint2*)&Ps[1 - p][kh * 32 + 16 + lm][nsw * 16 + q * 4] = *(uint2*)e1;\
        }                                                                         \
        if ((TT) < 62) KFP = *(const s8v*)(kbp + (size_t)((TT) + 2) * 2048);      \
        if ((TT) < 63) {                                                          \
            const ushort* vn = vfp + (size_t)((TT) + 1) * 16384;                  \
            _Pragma("unroll")                                                     \
            for (int ct = 0; ct < 4; ++ct)                                        \
                VNXT[ct] = *(const s8v*)(vn + ct * 512);                          \
        }                                                                         \
        s8v Af0 = *(const s8v*)&Ps[p][lm][kh * 32 + q * 8];                       \
        s8v Af1 = *(const s8v*)&Ps[p][16 + lm][kh * 32 + q * 8];                  \
        s8v Af2 = *(const s8v*)&Ps[p][32 + lm][kh * 32 + q * 8];                  \
        s8v Af3 = *(const s8v*)&Ps[p][48 + lm][kh * 32 + q * 8];                  \
        _Pragma("unroll")                                                         \
        for (int ct = 0; ct < 4; ++ct) {                                          \
            acc[0][ct] = __builtin_amdgcn_mfma_f32_16x16x32_bf16(Af0, VCUR[ct], acc[0][ct], 0, 0, 0); \
            acc[1][ct] = __builtin_amdgcn_mfma_f32_16x16x32_bf16(Af1, VCUR[ct], acc[1][ct], 0, 0, 0); \
            acc[2][ct] = __builtin_amdgcn_mfma_f32_16x16x32_bf16(Af2, VCUR[ct], acc[2][ct], 0, 0, 0); \
            acc[3][ct] = __builtin_amdgcn_mfma_f32_16x16x32_bf16(Af3, VCUR[ct], acc[3][ct], 0, 0, 0); \
        }                                                                         \
        __syncthreads();                                                          \
    }

    for (int t = 0; t < 64; t += 2) {
        TILE_BODY(t,     kf1, kf0, vfA, vfB);
        TILE_BODY(t + 1, kf0, kf1, vfB, vfA);
    }
#undef TILE_BODY

    // L: reduce over q groups (n-dir), then across nsw waves
    La0 += __shfl_xor(La0, 16, 64); La0 += __shfl_xor(La0, 32, 64);
    La1 += __shfl_xor(La1, 16, 64); La1 += __shfl_xor(La1, 32, 64);
    if (q == 0) {
        Lpart[nsw][kh * 32 + lm]      = La0;
        Lpart[nsw][kh * 32 + 16 + lm] = La1;
    }
    __syncthreads();
    if (tid < 64)
        Lrow[tid] = Lpart[0][tid] + Lpart[1][tid] + Lpart[2][tid] + Lpart[3][tid];
    __syncthreads();
    // combine k-halves through LDS
    #pragma unroll
    for (int ct = 0; ct < 4; ++ct) {
        if (kh == 1) {
            #pragma unroll
            for (int mt = 0; mt < 4; ++mt)
                #pragma unroll
                for (int r = 0; r < 4; ++r)
                    Obuf[nsw][mt * 16 + q * 4 + r][lm] = acc[mt][ct][r];
        }
        __syncthreads();
        if (kh == 0) {
            #pragma unroll
            for (int mt = 0; mt < 4; ++mt)
                #pragma unroll
                for (int r = 0; r < 4; ++r)
                    acc[mt][ct][r] += Obuf[nsw][mt * 16 + q * 4 + r][lm];
        }
        __syncthreads();
    }
    if (kh == 0) {
        float alpha = alphap[0];
        float ra = 1.f - alpha;
        #pragma unroll
        for (int mt = 0; mt < 4; ++mt) {
            float L0 = Lrow[mt * 16 + q * 4 + 0];
            float L1 = Lrow[mt * 16 + q * 4 + 1];
            float L2 = Lrow[mt * 16 + q * 4 + 2];
            float L3 = Lrow[mt * 16 + q * 4 + 3];
            #pragma unroll
            for (int ct = 0; ct < 4; ++ct) {
                int cc = nsw * 64 + ct * 16 + lm;
                size_t base = ((size_t)(b * 256 + cc)) * 4096 + m0 + mt * 16 + q * 4;
                float4 xv = *(const float4*)(x + base);
                float4 ov;
                ov.x = alpha * (acc[mt][ct][0] / L0) + ra * xv.x;
                ov.y = alpha * (acc[mt][ct][1] / L1) + ra * xv.y;
                ov.z = alpha * (acc[mt][ct][2] / L2) + ra * xv.z;
                ov.w = alpha * (acc[mt][ct][3] / L3) + ra * xv.w;
                *(float4*)(out + base) = ov;
            }
        }
    }
}

extern "C" void kernel_launch(void* const* d_in, const int* in_sizes, int n_in,
                              void* d_out, int out_size, void* d_ws, size_t ws_size,
                              hipStream_t stream) {
    const float* x  = (const float*)d_in[0];
    const float* wb = (const float*)d_in[1];
    const float* bb = (const float*)d_in[2];
    const float* wc = (const float*)d_in[3];
    const float* bc = (const float*)d_in[4];
    const float* wd = (const float*)d_in[5];
    const float* bd = (const float*)d_in[6];
    const float* al = (const float*)d_in[7];
    float* out = (float*)d_out;

    char* ws = (char*)d_ws;
    ushort* cat = (ushort*)ws;                    // 16 MiB
    ushort* Qb  = (ushort*)(ws + 16777216);       //  1 MiB
    ushort* Kb  = (ushort*)(ws + 17825792);       //  1 MiB
    ushort* Vf  = (ushort*)(ws + 18874368);       //  8 MiB (frag-ordered)
    ushort* Wf  = (ushort*)(ws + 27262976);       //  320 KiB (frag-ordered)

    pool_kernel<<<dim3(1104), dim3(256), 0, stream>>>(x, cat, wb, wc, wd, Wf);
    proj_kernel<<<dim3(512), dim3(256), 0, stream>>>(cat, Wf, bb, bc, bd,
                                                     Qb, Kb, Vf);
    attn_kernel<<<dim3(256), dim3(512), 0, stream>>>(Qb, Kb, Vf, x, al, out);
}